// Round 7
// baseline (141.531 us; speedup 1.0000x reference)
//
#include <hip/hip_runtime.h>
#include <hip/hip_bf16.h>

#define EMB 128
#define HID 11
#define PAIRS 2   // token-pairs per pipeline stage (4 tokens/stage)

typedef float f32x4 __attribute__((ext_vector_type(4)));

// tanh(x) = sign(x) * (1 - 2/(exp(2|x|)+1)); v_exp_f32 + v_rcp_f32 fast path.
__device__ __forceinline__ float fast_tanh(float x) {
    float ax = fabsf(x);
    float e  = __expf(2.0f * ax);
    float r  = 1.0f - 2.0f * __builtin_amdgcn_rcpf(e + 1.0f);
    return copysignf(r, x);
}

// R6 lesson (locked in): STRIDED token->wave map. Adjacent waves own adjacent
// 1KB output chunks -> the grid's instantaneous write front is one dense
// contiguous sweep (fill-kernel-like). Contiguous-per-wave spans (51KB apart)
// thrashed DRAM pages: 134us vs 95us.
// R7 single-variable test: plain stores instead of nontemporal for out_sum
// (NT was never isolated; the 6.9TB/s fill kernel uses plain stores).
// Wave layout: lanes 0..31 -> token 2w, lanes 32..63 -> token 2w+1; lane
// covers 4 emb columns (float4), c0=(lane&31)*4. One fast-tanh per token,
// h broadcast via __shfl within the half-wave. 1-stage software pipeline.
// __launch_bounds__(256,2): ~110 live VGPRs, no spill (R3 lesson).
__global__ __launch_bounds__(256, 2) void tabenc_kernel(
    const float* __restrict__ value,
    const int*   __restrict__ var_id,
    const int*   __restrict__ cmask,
    const float* __restrict__ W1,
    const float* __restrict__ b1,
    const float* __restrict__ W2,
    const float* __restrict__ emb,
    float*       __restrict__ out_sum,
    float*       __restrict__ out_pm,
    int n_tokens)
{
    const int tid  = threadIdx.x;
    const int lane = tid & 63;
    const int half = lane >> 5;
    const int sub  = lane & 31;
    const int sb   = lane & 32;      // shfl source base for this half-wave
    const int c0   = sub << 2;

    f32x4 w2[HID];
#pragma unroll
    for (int h = 0; h < HID; ++h)
        w2[h] = *reinterpret_cast<const f32x4*>(W2 + h * EMB + c0);

    float w1v = 0.0f, b1v = 0.0f;
    if (sub < HID) { w1v = W1[sub]; b1v = b1[sub]; }

    const int gwave  = (blockIdx.x << 2) + (tid >> 6);
    const int nwaves = gridDim.x << 2;
    const int nwS    = nwaves * PAIRS;      // stage stride in pair-index space
    const int npair  = (n_tokens + 1) >> 1;
    const int tmax   = n_tokens - 1;

    if (gwave >= npair) return;

    int   tokC[PAIRS]; bool actC[PAIRS]; float vC[PAIRS];
    int   idC[PAIRS];  float fmC[PAIRS];  f32x4 eC[PAIRS];
    int   tokN[PAIRS]; bool actN[PAIRS]; float vN[PAIRS];
    int   idN[PAIRS];  float fmN[PAIRS];  f32x4 eN[PAIRS];

    auto LOAD = [&](int wbase, int* tok, bool* act, float* v, int* id,
                    float* fm, f32x4* e) {
#pragma unroll
        for (int k = 0; k < PAIRS; ++k) {
            const int wk = wbase + k * nwaves;
            act[k] = (wk < npair);
            int t = 2 * wk + half;
            if (t > tmax) t = tmax;     // clamp: branch-free, dup loads only
            tok[k] = t;
            v[k]  = value[t];
            id[k] = var_id[t];
            fm[k] = (float)cmask[t];
        }
#pragma unroll
        for (int k = 0; k < PAIRS; ++k)
            e[k] = *reinterpret_cast<const f32x4*>(emb + (long)id[k] * EMB + c0);
    };

    LOAD(gwave, tokC, actC, vC, idC, fmC, eC);

    for (int w = gwave; w < npair; w += nwS) {
        // ---- prefetch next stage (clamped, unconditional) ----
        LOAD(w + nwS, tokN, actN, vN, idN, fmN, eN);

        // ---- compute current stage ----
        float hv[PAIRS];
#pragma unroll
        for (int k = 0; k < PAIRS; ++k)
            hv[k] = fast_tanh(fmaf(vC[k], w1v, b1v));

        f32x4 acc[PAIRS];
#pragma unroll
        for (int k = 0; k < PAIRS; ++k)
            acc[k] = (f32x4){0.f, 0.f, 0.f, 0.f};

#pragma unroll
        for (int hh = 0; hh < HID; ++hh) {
#pragma unroll
            for (int k = 0; k < PAIRS; ++k) {
                const float kk = __shfl(hv[k], sb + hh, 64);
                acc[k] += kk * w2[hh];
            }
        }

#pragma unroll
        for (int k = 0; k < PAIRS; ++k) {
            if (actC[k]) {
                const f32x4 o = acc[k] * fmC[k] + eC[k];
                *reinterpret_cast<f32x4*>(out_sum + (long)tokC[k] * EMB + c0) = o;
                if (sub == 0)
                    out_pm[tokC[k]] = (idC[k] > 0) ? 1.0f : 0.0f;
            }
        }

        // ---- rotate pipeline regs ----
#pragma unroll
        for (int k = 0; k < PAIRS; ++k) {
            tokC[k] = tokN[k]; actC[k] = actN[k]; vC[k] = vN[k];
            idC[k]  = idN[k];  fmC[k]  = fmN[k];  eC[k] = eN[k];
        }
    }
}

extern "C" void kernel_launch(void* const* d_in, const int* in_sizes, int n_in,
                              void* d_out, int out_size, void* d_ws, size_t ws_size,
                              hipStream_t stream) {
    const float* value  = (const float*)d_in[0];
    const int*   var_id = (const int*)  d_in[1];
    const int*   cmask  = (const int*)  d_in[2];
    const float* W1     = (const float*)d_in[3];
    const float* b1     = (const float*)d_in[4];
    const float* W2     = (const float*)d_in[5];
    const float* emb    = (const float*)d_in[6];

    const int n_tokens = in_sizes[0];              // 4096*200 = 819200
    float* out_sum = (float*)d_out;                // [n_tokens, 128]
    float* out_pm  = (float*)d_out + (long long)n_tokens * EMB;  // [n_tokens]

    const int waves_needed  = (n_tokens + 1) / 2;
    const int blocks_needed = (waves_needed + 3) / 4;
    const int grid = blocks_needed < 2048 ? blocks_needed : 2048;

    tabenc_kernel<<<grid, 256, 0, stream>>>(value, var_id, cmask, W1, b1, W2,
                                            emb, out_sum, out_pm, n_tokens);
}

// Round 8
// 102.463 us; speedup vs baseline: 1.3813x; 1.3813x over previous
//
#include <hip/hip_runtime.h>
#include <hip/hip_bf16.h>

#define EMB 128
#define HID 11

typedef float f32x4 __attribute__((ext_vector_type(4)));
typedef int   i32x4 __attribute__((ext_vector_type(4)));

// tanh(x) = sign(x) * (1 - 2/(exp(2|x|)+1)); v_exp_f32 + v_rcp_f32 fast path.
__device__ __forceinline__ float fast_tanh(float x) {
    float ax = fabsf(x);
    float e  = __expf(2.0f * ax);
    float r  = 1.0f - 2.0f * __builtin_amdgcn_rcpf(e + 1.0f);
    return copysignf(r, x);
}

// Separate fully-coalesced padding-mask pass: int4 load -> float4 NT store.
// Removes 400K masked partial-line dword stores (false-shared 128B lines
// across XCDs) from the main kernel's NT write stream.
__global__ __launch_bounds__(256) void pm_kernel(const int* __restrict__ var_id,
                                                 float* __restrict__ out_pm,
                                                 int n4, int n) {
    const int i = blockIdx.x * 256 + threadIdx.x;
    if (i < n4) {
        const i32x4 id4 = *(reinterpret_cast<const i32x4*>(var_id) + i);
        f32x4 pm;
        pm.x = (id4.x > 0) ? 1.0f : 0.0f;
        pm.y = (id4.y > 0) ? 1.0f : 0.0f;
        pm.z = (id4.z > 0) ? 1.0f : 0.0f;
        pm.w = (id4.w > 0) ? 1.0f : 0.0f;
        __builtin_nontemporal_store(pm, reinterpret_cast<f32x4*>(out_pm) + i);
    } else if (i == n4) {                 // tail (n % 4 elements)
        for (int t = n4 * 4; t < n; ++t)
            out_pm[t] = (var_id[t] > 0) ? 1.0f : 0.0f;
    }
}

// Main kernel. Locked-in lessons: STRIDED token->wave map (R6: contiguous
// spans thrash DRAM, 134us), NT stores for out_sum (R7: plain = +46us),
// no forced low VGPR cap (R3: spills). New in R8: PAIRS=1 with DEPTH-2
// software pipeline (same MLP at lower register state) and
// __launch_bounds__(256,5) -> VGPR cap ~102, target 5 waves/SIMD for more
// concurrent store streams; out_pm moved to pm_kernel.
// Wave layout: lanes 0..31 -> token 2w, lanes 32..63 -> token 2w+1; lane
// covers 4 emb columns (float4), c0=(lane&31)*4. One fast-tanh per token,
// h broadcast via __shfl within the half-wave.
__global__ __launch_bounds__(256, 5) void tabenc_kernel(
    const float* __restrict__ value,
    const int*   __restrict__ var_id,
    const int*   __restrict__ cmask,
    const float* __restrict__ W1,
    const float* __restrict__ b1,
    const float* __restrict__ W2,
    const float* __restrict__ emb,
    float*       __restrict__ out_sum,
    int n_tokens)
{
    const int tid  = threadIdx.x;
    const int lane = tid & 63;
    const int half = lane >> 5;
    const int sub  = lane & 31;
    const int sb   = lane & 32;      // shfl source base for this half-wave
    const int c0   = sub << 2;

    f32x4 w2[HID];
#pragma unroll
    for (int h = 0; h < HID; ++h)
        w2[h] = *reinterpret_cast<const f32x4*>(W2 + h * EMB + c0);

    float w1v = 0.0f, b1v = 0.0f;
    if (sub < HID) { w1v = W1[sub]; b1v = b1[sub]; }

    const int gwave  = (blockIdx.x << 2) + (tid >> 6);
    const int nwaves = gridDim.x << 2;
    const int npair  = (n_tokens + 1) >> 1;
    const int tmax   = n_tokens - 1;

    if (gwave >= npair) return;

    struct Stage { int tok; float v; int id; float fm; f32x4 e; };

    auto LOAD = [&](int w) -> Stage {
        Stage s;
        int t = 2 * w + half;
        if (t > tmax) t = tmax;      // clamp: branch-free dup loads only
        s.tok = t;
        s.v   = value[t];
        s.id  = var_id[t];
        s.fm  = (float)cmask[t];
        s.e   = *reinterpret_cast<const f32x4*>(emb + (long)s.id * EMB + c0);
        return s;
    };

    Stage s0 = LOAD(gwave);
    Stage s1 = LOAD(gwave + nwaves);

    for (int w = gwave; w < npair; w += nwaves) {
        // prefetch 2 stages ahead (clamped, unconditional)
        Stage s2 = LOAD(w + 2 * nwaves);

        // compute stage s0
        const float hv = fast_tanh(fmaf(s0.v, w1v, b1v));
        f32x4 acc = {0.f, 0.f, 0.f, 0.f};
#pragma unroll
        for (int hh = 0; hh < HID; ++hh) {
            const float kk = __shfl(hv, sb + hh, 64);
            acc += kk * w2[hh];
        }
        const f32x4 o = acc * s0.fm + s0.e;

        if (2 * w + half <= tmax)    // per-lane predicate; uniform per half
            __builtin_nontemporal_store(o,
                reinterpret_cast<f32x4*>(out_sum + (long)s0.tok * EMB + c0));

        s0 = s1; s1 = s2;
    }
}

extern "C" void kernel_launch(void* const* d_in, const int* in_sizes, int n_in,
                              void* d_out, int out_size, void* d_ws, size_t ws_size,
                              hipStream_t stream) {
    const float* value  = (const float*)d_in[0];
    const int*   var_id = (const int*)  d_in[1];
    const int*   cmask  = (const int*)  d_in[2];
    const float* W1     = (const float*)d_in[3];
    const float* b1     = (const float*)d_in[4];
    const float* W2     = (const float*)d_in[5];
    const float* emb    = (const float*)d_in[6];

    const int n_tokens = in_sizes[0];              // 4096*200 = 819200
    float* out_sum = (float*)d_out;                // [n_tokens, 128]
    float* out_pm  = (float*)d_out + (long long)n_tokens * EMB;  // [n_tokens]

    // main kernel: strided pair map, 2048 blocks x 4 waves
    const int waves_needed  = (n_tokens + 1) / 2;
    const int blocks_needed = (waves_needed + 3) / 4;
    const int grid = blocks_needed < 2048 ? blocks_needed : 2048;
    tabenc_kernel<<<grid, 256, 0, stream>>>(value, var_id, cmask, W1, b1, W2,
                                            emb, out_sum, n_tokens);

    // padding-mask pass: coalesced int4 -> float4
    const int n4 = n_tokens >> 2;
    const int pm_threads = n4 + 1;                 // +1 thread for tail
    const int pm_blocks = (pm_threads + 255) / 256;
    pm_kernel<<<pm_blocks, 256, 0, stream>>>(var_id, out_pm, n4, n_tokens);
}